// Round 1
// baseline (936.089 us; speedup 1.0000x reference)
//
#include <hip/hip_runtime.h>

#define NSEG 2048
#define EPS 1e-6f

__device__ __forceinline__ float wave_reduce(float x) {
    #pragma unroll
    for (int off = 32; off > 0; off >>= 1) x += __shfl_down(x, off, 64);
    return x;
}

__global__ void zero_ws_kernel(float* __restrict__ ws, int n) {
    int i = blockIdx.x * blockDim.x + threadIdx.x;
    if (i < n) ws[i] = 0.0f;
}

// Pass 1: per-segment accumulation of
//   sum_s  = sum over nodes of sum_c s[i,c]
//   sum_q  = sum over nodes of sum_c s[i,c]^2
//   sum_v  = sum over nodes of sum_{d,c} v[i,d,c]^2
//   cnt    = node count
// One wave handles a contiguous chunk of nodes; batch is sorted so
// flushes (shuffle-reduce + atomics) happen only at segment boundaries.
__global__ void pass1_kernel(const float* __restrict__ s,
                             const float* __restrict__ v,
                             const int* __restrict__ batch,
                             float* __restrict__ ws, int n) {
    const int lane  = threadIdx.x & 63;
    const int wave  = (blockIdx.x * blockDim.x + threadIdx.x) >> 6;
    const int nwav  = (gridDim.x * blockDim.x) >> 6;
    const int chunk = (n + nwav - 1) / nwav;
    const int start = wave * chunk;
    const int end   = min(start + chunk, n);
    if (start >= end) return;

    float* sum_s = ws;
    float* sum_q = ws + NSEG;
    float* sum_v = ws + 2 * NSEG;
    float* cntp  = ws + 3 * NSEG;

    float ls = 0.0f, lq = 0.0f, lv = 0.0f;
    int run = 0;
    int cur = -1;

    for (int i = start; i < end; ++i) {
        const int g = batch[i];
        if (g != cur) {
            if (run > 0) {
                float rs = wave_reduce(ls);
                float rq = wave_reduce(lq);
                float rv = wave_reduce(lv);
                if (lane == 0) {
                    atomicAdd(&sum_s[cur], rs);
                    atomicAdd(&sum_q[cur], rq);
                    atomicAdd(&sum_v[cur], rv);
                    atomicAdd(&cntp[cur], (float)run);
                }
            }
            ls = lq = lv = 0.0f;
            run = 0;
            cur = g;
        }
        const float4 x = ((const float4*)(s + (size_t)i * 256))[lane];
        ls += x.x + x.y + x.z + x.w;
        lq += x.x * x.x + x.y * x.y + x.z * x.z + x.w * x.w;
        const float4 y = ((const float4*)(v + (size_t)i * 384))[lane];
        lv += y.x * y.x + y.y * y.y + y.z * y.z + y.w * y.w;
        const float2 z = ((const float2*)(v + (size_t)i * 384 + 256))[lane];
        lv += z.x * z.x + z.y * z.y;
        ++run;
    }
    if (run > 0) {
        float rs = wave_reduce(ls);
        float rq = wave_reduce(lq);
        float rv = wave_reduce(lv);
        if (lane == 0) {
            atomicAdd(&sum_s[cur], rs);
            atomicAdd(&sum_q[cur], rq);
            atomicAdd(&sum_v[cur], rv);
            atomicAdd(&cntp[cur], (float)run);
        }
    }
}

// Finalize: smean, 1/var, 1/vmean per segment.
// var = E[mean_c s^2] - smean^2  (algebraic expansion of reference).
__global__ void finalize_kernel(float* __restrict__ ws) {
    int g = blockIdx.x * blockDim.x + threadIdx.x;
    if (g >= NSEG) return;
    float n   = fmaxf(ws[3 * NSEG + g], 1.0f);
    float sm  = ws[g] / (256.0f * n);
    float es2 = ws[NSEG + g] / (256.0f * n);
    float var = fmaxf(es2 - sm * sm, EPS);
    float vm  = fmaxf(ws[2 * NSEG + g] / (128.0f * n), EPS);
    ws[4 * NSEG + g] = sm;
    ws[5 * NSEG + g] = 1.0f / var;
    ws[6 * NSEG + g] = 1.0f / vm;
}

// Pass 2: apply normalization, coalesced float4 IO, one wave per node.
__global__ void pass2_kernel(const float* __restrict__ s,
                             const float* __restrict__ v,
                             const int* __restrict__ batch,
                             const float* __restrict__ weight,
                             const float* __restrict__ bias,
                             const float* __restrict__ ws,
                             float* __restrict__ out, int n) {
    const int lane  = threadIdx.x & 63;
    const int wave  = (blockIdx.x * blockDim.x + threadIdx.x) >> 6;
    const int nwav  = (gridDim.x * blockDim.x) >> 6;
    const int chunk = (n + nwav - 1) / nwav;
    const int start = wave * chunk;
    const int end   = min(start + chunk, n);
    if (start >= end) return;

    const float* smean = ws + 4 * NSEG;
    const float* ivar  = ws + 5 * NSEG;
    const float* ivmn  = ws + 6 * NSEG;

    const float4 w4 = ((const float4*)weight)[lane];
    const float4 b4 = ((const float4*)bias)[lane];

    float* sout = out;
    float* vout = out + (size_t)n * 256;

    for (int i = start; i < end; ++i) {
        const int g = batch[i];
        const float sm = smean[g];
        const float iv = ivar[g];
        const float im = ivmn[g];

        const float4 x = ((const float4*)(s + (size_t)i * 256))[lane];
        float4 o;
        o.x = (x.x - sm) * iv * w4.x + b4.x;
        o.y = (x.y - sm) * iv * w4.y + b4.y;
        o.z = (x.z - sm) * iv * w4.z + b4.z;
        o.w = (x.w - sm) * iv * w4.w + b4.w;
        ((float4*)(sout + (size_t)i * 256))[lane] = o;

        float4 y = ((const float4*)(v + (size_t)i * 384))[lane];
        y.x *= im; y.y *= im; y.z *= im; y.w *= im;
        ((float4*)(vout + (size_t)i * 384))[lane] = y;

        float2 z = ((const float2*)(v + (size_t)i * 384 + 256))[lane];
        z.x *= im; z.y *= im;
        ((float2*)(vout + (size_t)i * 384 + 256))[lane] = z;
    }
}

extern "C" void kernel_launch(void* const* d_in, const int* in_sizes, int n_in,
                              void* d_out, int out_size, void* d_ws, size_t ws_size,
                              hipStream_t stream) {
    const float* s      = (const float*)d_in[0];
    const float* v      = (const float*)d_in[1];
    const float* weight = (const float*)d_in[2];
    const float* bias   = (const float*)d_in[3];
    const int*   batch  = (const int*)d_in[4];
    float* out = (float*)d_out;
    float* ws  = (float*)d_ws;

    const int n = in_sizes[0] / 256;  // number of nodes

    // zero the 4*NSEG accumulators
    zero_ws_kernel<<<(4 * NSEG + 255) / 256, 256, 0, stream>>>(ws, 4 * NSEG);

    // pass 1: segment statistics
    pass1_kernel<<<1024, 256, 0, stream>>>(s, v, batch, ws, n);

    // finalize per-segment params
    finalize_kernel<<<(NSEG + 255) / 256, 256, 0, stream>>>(ws);

    // pass 2: apply
    pass2_kernel<<<1024, 256, 0, stream>>>(s, v, batch, weight, bias, ws, out, n);
}